// Round 8
// baseline (404.953 us; speedup 1.0000x reference)
//
#include <hip/hip_runtime.h>
#include <math.h>

// MMGCN: GEMM pushed through the (linear) aggregation + LDS-free bf16 MFMA GEMMs.
//   z1  = A . (xn*onrm)                      [shared by v,t]   -> conv1 GEMM K=128 (MFMA)
//   zlx = A . leaky(xn*onrm)                 [shared by v,t]   -> conv2 top half
//   zx  = A . leaky(xhat_{v,t}*onrm) interleaved               -> conv2 bottom half
//   out256 = ([zlx | zx] @ B2)*in_norm + 0.5(b1v+b1t) + gid    -> one K=384 GEMM (MFMA)
// GEMMs load MFMA fragments DIRECTLY from global; 64-row blocks (1563 of them) give
// ~24 waves/CU so HBM latency is hidden by TLP (the 128-row version sat at 12 waves/CU,
// 23% occupancy, 1.3 TB/s — latency-bound).

typedef unsigned int uint;
typedef unsigned short ushort;
using bf16x8 = __attribute__((ext_vector_type(8))) short;
using f32x4  = __attribute__((ext_vector_type(4))) float;

__device__ __forceinline__ float lrelu(float v) { return v >= 0.0f ? v : 0.01f * v; }
__device__ __forceinline__ float bf2f(uint us) { return __uint_as_float(us << 16); }
__device__ __forceinline__ ushort f2bf(float f) {
    uint u = __float_as_uint(f);
    u += 0x7fffu + ((u >> 16) & 1u);   // round-to-nearest-even
    return (ushort)(u >> 16);
}

// ---------------- degree histograms ----------------
__global__ void k_degrees(const int* __restrict__ src, const int* __restrict__ dst,
                          int* __restrict__ deg_out, int* __restrict__ deg_in, int E) {
    int e = blockIdx.x * blockDim.x + threadIdx.x;
    if (e < E) {
        atomicAdd(&deg_out[src[e]], 1);
        atomicAdd(&deg_in[dst[e]], 1);
    }
}

__global__ void k_norms(const int* __restrict__ deg_out, const int* __restrict__ deg_in,
                        float* __restrict__ onrm, float* __restrict__ inrm, int n) {
    int i = blockIdx.x * blockDim.x + threadIdx.x;
    if (i < n) {
        onrm[i] = 1.0f / sqrtf((float)max(deg_out[i], 1));
        inrm[i] = 1.0f / sqrtf((float)max(deg_in[i], 1));
    }
}

// ---------------- multi-block prefix scan: deg_in -> row_ptr ----------------
__global__ void k_scan1(const int* __restrict__ deg, int* __restrict__ row_ptr,
                        int* __restrict__ csum, int n) {
    __shared__ int wsum[16];
    __shared__ int wpre[16];
    int lane = threadIdx.x & 63;
    int wid  = threadIdx.x >> 6;
    int i = blockIdx.x * 1024 + threadIdx.x;
    int v = (i < n) ? deg[i] : 0;
    int s = v;
    #pragma unroll
    for (int off = 1; off < 64; off <<= 1) {
        int t = __shfl_up(s, off, 64);
        if (lane >= off) s += t;
    }
    if (lane == 63) wsum[wid] = s;
    __syncthreads();
    if (wid == 0) {
        int wv = (lane < 16) ? wsum[lane] : 0;
        int ss = wv;
        #pragma unroll
        for (int off = 1; off < 16; off <<= 1) {
            int t = __shfl_up(ss, off, 64);
            if (lane >= off) ss += t;
        }
        if (lane < 16) wpre[lane] = ss - wv;
    }
    __syncthreads();
    int incl = s + wpre[wid];
    if (i < n) row_ptr[i + 1] = incl;                        // chunk-local for now
    if (threadIdx.x == 1023) csum[blockIdx.x] = incl;        // chunk total
}

__global__ void k_scan2(int* __restrict__ csum, int nb) {
    __shared__ int wsum[16];
    __shared__ int wpre[16];
    int lane = threadIdx.x & 63;
    int wid  = threadIdx.x >> 6;
    int i = threadIdx.x;
    int v = (i < nb) ? csum[i] : 0;
    int s = v;
    #pragma unroll
    for (int off = 1; off < 64; off <<= 1) {
        int t = __shfl_up(s, off, 64);
        if (lane >= off) s += t;
    }
    if (lane == 63) wsum[wid] = s;
    __syncthreads();
    if (wid == 0) {
        int wv = (lane < 16) ? wsum[lane] : 0;
        int ss = wv;
        #pragma unroll
        for (int off = 1; off < 16; off <<= 1) {
            int t = __shfl_up(ss, off, 64);
            if (lane >= off) ss += t;
        }
        if (lane < 16) wpre[lane] = ss - wv;
    }
    __syncthreads();
    if (i < nb) csum[i] = s + wpre[wid];
}

__global__ void k_scan3(int* __restrict__ row_ptr, const int* __restrict__ csum, int n) {
    int i = blockIdx.x * blockDim.x + threadIdx.x;
    if (i == 0) row_ptr[0] = 0;
    if (i < n) {
        int b = i >> 10;
        if (b > 0) row_ptr[i + 1] += csum[b - 1];
    }
}

__global__ void k_fill(const int* __restrict__ src, const int* __restrict__ dst,
                       const int* __restrict__ row_ptr, int* __restrict__ cursor,
                       int* __restrict__ col, int E) {
    int e = blockIdx.x * blockDim.x + threadIdx.x;
    if (e < E) {
        int d = dst[e];
        int pos = atomicAdd(&cursor[d], 1);
        col[row_ptr[d] + pos] = src[e];
    }
}

// ---------------- weight prep ----------------
// W1T [256 cols][128 k]: cols 0:128 = Wv0 cols; 128:256 = Wt0 cols  (de-interleaved)
// W2T [128 cols][384 k]: k 0:128 = 0.5(Wv1+Wt1); k 128+2q+b = 0.5 Wb1[128+q]  (interleaved)
__global__ void k_wprep(const float* __restrict__ Wv0, const float* __restrict__ Wt0,
                        const float* __restrict__ Wv1, const float* __restrict__ Wt1,
                        const float* __restrict__ bv0, const float* __restrict__ bt0,
                        const float* __restrict__ bv1, const float* __restrict__ bt1,
                        ushort* __restrict__ W1T, ushort* __restrict__ W2T,
                        float* __restrict__ bias_cat, float* __restrict__ bias2) {
    int t = blockIdx.x * blockDim.x + threadIdx.x;
    if (t < 256 * 128) {
        int c = t >> 7, k = t & 127;
        float v = (c < 128) ? Wv0[k * 128 + c] : Wt0[k * 128 + (c - 128)];
        W1T[c * 128 + k] = f2bf(v);
    }
    if (t < 128 * 384) {
        int c = t / 384, r = t % 384;
        float v;
        if (r < 128) v = 0.5f * (Wv1[r * 128 + c] + Wt1[r * 128 + c]);
        else {
            int q = (r - 128) >> 1;
            v = 0.5f * (((r - 128) & 1) ? Wt1[(128 + q) * 128 + c] : Wv1[(128 + q) * 128 + c]);
        }
        W2T[c * 384 + r] = f2bf(v);
    }
    if (t < 256) bias_cat[t] = (t < 128) ? bv0[t] : bt0[t - 128];
    if (t < 128) bias2[t] = 0.5f * (bv1[t] + bt1[t]);
}

// ------- row L2-normalize x; out[:,0:128]=leaky(xn); xn_sc=xn*onrm (bf16); gid bf16 -------
__global__ void k_normx(const float* __restrict__ x, const float* __restrict__ onrm,
                        const int* __restrict__ dsti, const float* __restrict__ id_emb,
                        ushort* __restrict__ xn_sc, ushort* __restrict__ gid,
                        float* __restrict__ out, int n) {
    int gtid = blockIdx.x * blockDim.x + threadIdx.x;
    int row  = gtid >> 6;
    int lane = gtid & 63;
    if (row >= n) return;
    int c = lane * 2;
    float2 v = *(const float2*)&x[(size_t)row * 128 + c];
    float s = v.x * v.x + v.y * v.y;
    #pragma unroll
    for (int off = 1; off < 64; off <<= 1) s += __shfl_xor(s, off, 64);
    float scale = 1.0f / fmaxf(sqrtf(s), 1e-12f);
    float nx = v.x * scale, ny = v.y * scale;
    *(float2*)&out[(size_t)row * 384 + c] = make_float2(lrelu(nx), lrelu(ny));
    float so = onrm[row];
    uint p = (uint)f2bf(nx * so) | ((uint)f2bf(ny * so) << 16);
    *(uint*)&xn_sc[(size_t)row * 128 + c] = p;
    // densify id_emb[dsti[row]] -> gid[row] (bf16)
    int g = dsti[row];
    float2 ge = *(const float2*)&id_emb[(size_t)g * 128 + c];
    uint pg = (uint)f2bf(ge.x) | ((uint)f2bf(ge.y) << 16);
    *(uint*)&gid[(size_t)row * 128 + c] = pg;
}

// ---------------- gather pass 1: z1 = A.xn_sc ; zlx = A.leaky(xn_sc)  (both bf16) -------
__global__ void k_agg1(const ushort* __restrict__ xn_sc, const int* __restrict__ rp,
                       const int* __restrict__ col, ushort* __restrict__ z1,
                       ushort* __restrict__ zbig, int n) {
    int gtid = blockIdx.x * blockDim.x + threadIdx.x;
    int row  = gtid >> 6;
    int lane = gtid & 63;
    if (row >= n) return;
    int c = lane * 2;
    float zx = 0.f, zy = 0.f, lx = 0.f, ly = 0.f;
    int e0 = rp[row], e1 = rp[row + 1];
    int e = e0;
    for (; e + 1 < e1; e += 2) {
        int s0 = col[e], s1 = col[e + 1];
        uint v0 = *(const uint*)&xn_sc[(size_t)s0 * 128 + c];
        uint v1 = *(const uint*)&xn_sc[(size_t)s1 * 128 + c];
        float ax = bf2f(v0 & 0xffffu), ay = bf2f(v0 >> 16);
        float bx = bf2f(v1 & 0xffffu), by = bf2f(v1 >> 16);
        zx += ax + bx; zy += ay + by;
        lx += lrelu(ax) + lrelu(bx); ly += lrelu(ay) + lrelu(by);
    }
    if (e < e1) {
        uint v0 = *(const uint*)&xn_sc[(size_t)col[e] * 128 + c];
        float ax = bf2f(v0 & 0xffffu), ay = bf2f(v0 >> 16);
        zx += ax; zy += ay; lx += lrelu(ax); ly += lrelu(ay);
    }
    *(uint*)&z1[(size_t)row * 128 + c]  = (uint)f2bf(zx) | ((uint)f2bf(zy) << 16);
    *(uint*)&zbig[(size_t)row * 384 + c] = (uint)f2bf(lx) | ((uint)f2bf(ly) << 16);
}

// ---------------- gather pass 2: zx_inter = A.xhat_sc  (256-wide, bf16) ----------------
__global__ void k_agg2(const ushort* __restrict__ xhat_sc, const int* __restrict__ rp,
                       const int* __restrict__ col, ushort* __restrict__ zbig, int n) {
    int gtid = blockIdx.x * blockDim.x + threadIdx.x;
    int row  = gtid >> 6;
    int lane = gtid & 63;
    if (row >= n) return;
    int c = lane * 4;
    float a0 = 0.f, a1 = 0.f, a2 = 0.f, a3 = 0.f;
    int e0 = rp[row], e1 = rp[row + 1];
    int e = e0;
    for (; e + 1 < e1; e += 2) {
        int s0 = col[e], s1 = col[e + 1];
        uint2 v0 = *(const uint2*)&xhat_sc[(size_t)s0 * 256 + c];
        uint2 v1 = *(const uint2*)&xhat_sc[(size_t)s1 * 256 + c];
        a0 += bf2f(v0.x & 0xffffu) + bf2f(v1.x & 0xffffu);
        a1 += bf2f(v0.x >> 16)     + bf2f(v1.x >> 16);
        a2 += bf2f(v0.y & 0xffffu) + bf2f(v1.y & 0xffffu);
        a3 += bf2f(v0.y >> 16)     + bf2f(v1.y >> 16);
    }
    if (e < e1) {
        uint2 v0 = *(const uint2*)&xhat_sc[(size_t)col[e] * 256 + c];
        a0 += bf2f(v0.x & 0xffffu); a1 += bf2f(v0.x >> 16);
        a2 += bf2f(v0.y & 0xffffu); a3 += bf2f(v0.y >> 16);
    }
    uint2 p;
    p.x = (uint)f2bf(a0) | ((uint)f2bf(a1) << 16);
    p.y = (uint)f2bf(a2) | ((uint)f2bf(a3) << 16);
    *(uint2*)&zbig[(size_t)row * 384 + 128 + c] = p;
}

// ---------------- conv1 MFMA GEMM, LDS-free: 64 rows x 256 cols per block ----------------
// 4 waves 2x2; wave = 32 rows x (64 v-cols + matching 64 t-cols).
__global__ __launch_bounds__(256) void k_gemm1(
    const ushort* __restrict__ A, const ushort* __restrict__ WT,
    const float* __restrict__ inrm, const float* __restrict__ onrm,
    const ushort* __restrict__ gid, const float* __restrict__ bias,
    ushort* __restrict__ xhat_sc, float* __restrict__ out, int n)
{
    int tid  = threadIdx.x;
    int lane = tid & 63;
    int w    = tid >> 6;
    int wm   = w >> 1, wn = w & 1;
    int row0 = blockIdx.x * 64;
    int lr = lane & 15;
    int lk = lane >> 4;

    f32x4 acc[2][8];
    f32x4 zero = {0.f, 0.f, 0.f, 0.f};
    #pragma unroll
    for (int m = 0; m < 2; m++)
        #pragma unroll
        for (int nn = 0; nn < 8; nn++) acc[m][nn] = zero;

    int rg[2]; bool ok[2];
    #pragma unroll
    for (int m = 0; m < 2; m++) { rg[m] = row0 + wm * 32 + m * 16 + lr; ok[m] = rg[m] < n; }
    bf16x8 zf = {0, 0, 0, 0, 0, 0, 0, 0};

    #pragma unroll
    for (int ks = 0; ks < 4; ks++) {
        int koff = ks * 32 + lk * 8;
        bf16x8 af[2], bf[8];
        #pragma unroll
        for (int m = 0; m < 2; m++)
            af[m] = ok[m] ? *(const bf16x8*)&A[(size_t)rg[m] * 128 + koff] : zf;
        #pragma unroll
        for (int nn = 0; nn < 4; nn++) {
            int cv = wn * 64 + nn * 16 + lr;
            bf[nn]     = *(const bf16x8*)&WT[(size_t)cv * 128 + koff];
            bf[nn + 4] = *(const bf16x8*)&WT[(size_t)(128 + cv) * 128 + koff];
        }
        #pragma unroll
        for (int m = 0; m < 2; m++)
            #pragma unroll
            for (int nn = 0; nn < 8; nn++)
                acc[m][nn] = __builtin_amdgcn_mfma_f32_16x16x32_bf16(af[m], bf[nn], acc[m][nn], 0, 0, 0);
    }

    #pragma unroll
    for (int m = 0; m < 2; m++) {
        int rb = row0 + wm * 32 + m * 16 + lk * 4;
        #pragma unroll
        for (int nn = 0; nn < 4; nn++) {
            int cv = wn * 64 + nn * 16 + lr;          // 0..127
            float biv = bias[cv];
            float bit = bias[128 + cv];
            #pragma unroll
            for (int j = 0; j < 4; j++) {
                int r = rb + j;
                if (r >= n) continue;
                float win = inrm[r];
                float won = onrm[r];
                float ge = bf2f((uint)gid[(size_t)r * 128 + cv]);
                float tv = acc[m][nn][j] * win + biv + ge;
                float tt = acc[m][nn + 4][j] * win + bit + ge;
                float lv = lrelu(tv), lt = lrelu(tt);
                out[(size_t)r * 384 + 128 + cv] = 0.5f * (lv + lt);
                uint pk = (uint)f2bf(lv * won) | ((uint)f2bf(lt * won) << 16);
                *(uint*)&xhat_sc[(size_t)r * 256 + 2 * cv] = pk;
            }
        }
    }
}

// ---------------- conv2 MFMA GEMM, LDS-free: 64 rows x 128 cols per block, K=384 --------
__global__ __launch_bounds__(256) void k_gemm2(
    const ushort* __restrict__ A, const ushort* __restrict__ WT,
    const float* __restrict__ inrm, const ushort* __restrict__ gid,
    const float* __restrict__ bias, float* __restrict__ out, int n)
{
    int tid  = threadIdx.x;
    int lane = tid & 63;
    int w    = tid >> 6;
    int wm   = w >> 1, wn = w & 1;
    int row0 = blockIdx.x * 64;
    int lr = lane & 15;
    int lk = lane >> 4;

    f32x4 acc[2][4];
    f32x4 zero = {0.f, 0.f, 0.f, 0.f};
    #pragma unroll
    for (int m = 0; m < 2; m++)
        #pragma unroll
        for (int nn = 0; nn < 4; nn++) acc[m][nn] = zero;

    int rg[2]; bool ok[2];
    #pragma unroll
    for (int m = 0; m < 2; m++) { rg[m] = row0 + wm * 32 + m * 16 + lr; ok[m] = rg[m] < n; }
    bf16x8 zf = {0, 0, 0, 0, 0, 0, 0, 0};

    #pragma unroll
    for (int ks = 0; ks < 12; ks++) {
        int koff = ks * 32 + lk * 8;
        bf16x8 af[2], bf[4];
        #pragma unroll
        for (int m = 0; m < 2; m++)
            af[m] = ok[m] ? *(const bf16x8*)&A[(size_t)rg[m] * 384 + koff] : zf;
        #pragma unroll
        for (int nn = 0; nn < 4; nn++) {
            int cg = wn * 64 + nn * 16 + lr;
            bf[nn] = *(const bf16x8*)&WT[(size_t)cg * 384 + koff];
        }
        #pragma unroll
        for (int m = 0; m < 2; m++)
            #pragma unroll
            for (int nn = 0; nn < 4; nn++)
                acc[m][nn] = __builtin_amdgcn_mfma_f32_16x16x32_bf16(af[m], bf[nn], acc[m][nn], 0, 0, 0);
    }

    #pragma unroll
    for (int m = 0; m < 2; m++) {
        int rb = row0 + wm * 32 + m * 16 + lk * 4;
        #pragma unroll
        for (int nn = 0; nn < 4; nn++) {
            int cg = wn * 64 + nn * 16 + lr;
            float bi = bias[cg];
            #pragma unroll
            for (int j = 0; j < 4; j++) {
                int r = rb + j;
                if (r >= n) continue;
                float ge = bf2f((uint)gid[(size_t)r * 128 + cg]);
                float t = acc[m][nn][j] * inrm[r] + bi + ge;
                out[(size_t)r * 384 + 256 + cg] = t;
            }
        }
    }
}

extern "C" void kernel_launch(void* const* d_in, const int* in_sizes, int n_in,
                              void* d_out, int out_size, void* d_ws, size_t ws_size,
                              hipStream_t stream) {
    const float* x      = (const float*)d_in[0];
    const float* id_emb = (const float*)d_in[1];
    const float* Wv0    = (const float*)d_in[2];
    const float* bv0    = (const float*)d_in[3];
    const float* Wv1    = (const float*)d_in[4];
    const float* bv1    = (const float*)d_in[5];
    const float* Wt0    = (const float*)d_in[6];
    const float* bt0    = (const float*)d_in[7];
    const float* Wt1    = (const float*)d_in[8];
    const float* bt1    = (const float*)d_in[9];
    const int*   src    = (const int*)d_in[10];
    const int*   dst    = (const int*)d_in[11];
    const int*   dsti   = (const int*)d_in[12];
    const int E = in_sizes[10];
    const int N = in_sizes[12];
    float* out = (float*)d_out;

    char* p = (char*)d_ws;
    ushort* xn_sc   = (ushort*)p; p += (size_t)N * 128 * 2;
    ushort* xhat_sc = (ushort*)p; p += (size_t)N * 256 * 2;
    ushort* z1      = (ushort*)p; p += (size_t)N * 128 * 2;
    ushort* zbig    = (ushort*)p; p += (size_t)N * 384 * 2;
    ushort* gid     = (ushort*)p; p += (size_t)N * 128 * 2;
    ushort* W1T     = (ushort*)p; p += 256 * 128 * 2;
    ushort* W2T     = (ushort*)p; p += 128 * 384 * 2;
    float* bias_cat = (float*)p;  p += 256 * 4;
    float* bias2    = (float*)p;  p += 128 * 4;
    float* onrm     = (float*)p;  p += (size_t)N * 4;
    float* inrm     = (float*)p;  p += (size_t)N * 4;
    int* deg_out    = (int*)p;    p += (size_t)N * 4;
    int* deg_in     = (int*)p;    p += (size_t)N * 4;
    int* cursor     = (int*)p;    p += (size_t)N * 4;
    int* row_ptr    = (int*)p;    p += (size_t)(N + 1) * 4;
    int* csum       = (int*)p;    p += 1024 * 4;
    int* col        = (int*)p;    p += (size_t)E * 4;

    hipMemsetAsync(deg_out, 0, (size_t)N * 3 * 4, stream);   // deg_out|deg_in|cursor contiguous

    int be = (E + 255) / 256;
    int bn = (N + 255) / 256;
    int bw = (N * 64 + 255) / 256;          // one wave per row
    int bg = (N + 63) / 64;                 // 64-row GEMM tiles
    int nb = (N + 1023) / 1024;             // scan chunks

    k_degrees<<<be, 256, 0, stream>>>(src, dst, deg_out, deg_in, E);
    k_norms  <<<bn, 256, 0, stream>>>(deg_out, deg_in, onrm, inrm, N);
    k_scan1  <<<nb, 1024, 0, stream>>>(deg_in, row_ptr, csum, N);
    k_scan2  <<<1, 1024, 0, stream>>>(csum, nb);
    k_scan3  <<<bn, 256, 0, stream>>>(row_ptr, csum, N);
    k_fill   <<<be, 256, 0, stream>>>(src, dst, row_ptr, cursor, col, E);
    k_wprep  <<<192, 256, 0, stream>>>(Wv0, Wt0, Wv1, Wt1, bv0, bt0, bv1, bt1,
                                       W1T, W2T, bias_cat, bias2);
    k_normx  <<<bw, 256, 0, stream>>>(x, onrm, dsti, id_emb, xn_sc, gid, out, N);

    k_agg1 <<<bw, 256, 0, stream>>>(xn_sc, row_ptr, col, z1, zbig, N);
    k_gemm1<<<bg, 256, 0, stream>>>(z1, W1T, inrm, onrm, gid, bias_cat, xhat_sc, out, N);
    k_agg2 <<<bw, 256, 0, stream>>>(xhat_sc, row_ptr, col, zbig, N);
    k_gemm2<<<bg, 256, 0, stream>>>(zbig, W2T, inrm, gid, bias2, out, N);
}